// Round 1
// baseline (627.349 us; speedup 1.0000x reference)
//
#include <hip/hip_runtime.h>

// VectorQuantizer: inputs [8,2048,128] f32, embeddings [128,8192] f32
// d_out (all f32, concatenated): quantized [16384*128], encodings [16384*8192],
// indices [16384], loss [1]
#define D 128
#define K 8192
#define N 16384
#define RT 32              // rows per block
#define CT 128             // codebook cols per chunk
#define NCHUNK (K / CT)    // 64
#define THREADS 256
#define MAIN_BLOCKS (N / RT)  // 512

__global__ __launch_bounds__(256) void enorm_kernel(const float* __restrict__ E,
                                                    float* __restrict__ enorm) {
    int k = blockIdx.x * 256 + threadIdx.x;
    float s = 0.f;
#pragma unroll 8
    for (int d = 0; d < D; ++d) {
        float v = E[(size_t)d * K + k];
        s += v * v;
    }
    enorm[k] = s;
}

__global__ __launch_bounds__(256, 2) void main_kernel(const float* __restrict__ X,
                                                      const float* __restrict__ E,
                                                      const float* __restrict__ enorm,
                                                      float* __restrict__ out,
                                                      float* __restrict__ partials) {
    __shared__ float x_s[D][RT];   // 16 KB, transposed: x_s[d][row]
    __shared__ float e_s[D][CT];   // 64 KB: e_s[d][col]

    const int t = threadIdx.x;
    const int bid = blockIdx.x;
    const int brow = bid * RT;

    float* qout = out;
    float* enc = out + (size_t)N * D;
    float* idxout = out + (size_t)N * D + (size_t)N * K;

    // ---- stage X tile (coalesced global float4, transposed scatter to LDS) ----
#pragma unroll
    for (int j = 0; j < (RT * D / 4) / THREADS; ++j) {   // 4
        int h = t + THREADS * j;
        int row = h >> 5;
        int d4 = (h & 31) << 2;
        const float4 v = *reinterpret_cast<const float4*>(&X[(size_t)(brow + row) * D + d4]);
        x_s[d4 + 0][row] = v.x;
        x_s[d4 + 1][row] = v.y;
        x_s[d4 + 2][row] = v.z;
        x_s[d4 + 3][row] = v.w;
    }

    const int txr = t & 3;    // row group: rows 8*txr .. 8*txr+7
    const int tyc = t >> 2;   // col group: cols 2*tyc, 2*tyc+1

    float bestd[8];
    int bestk[8];
#pragma unroll
    for (int i = 0; i < 8; ++i) { bestd[i] = 1e30f; bestk[i] = 0; }

    for (int ch = 0; ch < NCHUNK; ++ch) {
        const int kbase = ch * CT;
        __syncthreads();
        // ---- stage E chunk: [D][CT], linear conflict-free LDS writes ----
#pragma unroll
        for (int j = 0; j < (CT * D / 4) / THREADS; ++j) {  // 16
            int h = t + THREADS * j;
            int d = h >> 5;
            int c4 = (h & 31) << 2;
            const float4 v = *reinterpret_cast<const float4*>(&E[(size_t)d * K + kbase + c4]);
            *reinterpret_cast<float4*>(&e_s[d][c4]) = v;
        }
        __syncthreads();

        float acc[8][2];
#pragma unroll
        for (int i = 0; i < 8; ++i) { acc[i][0] = 0.f; acc[i][1] = 0.f; }

#pragma unroll 8
        for (int d = 0; d < D; ++d) {
            const float4 xa = *reinterpret_cast<const float4*>(&x_s[d][8 * txr]);
            const float4 xb = *reinterpret_cast<const float4*>(&x_s[d][8 * txr + 4]);
            const float2 ev = *reinterpret_cast<const float2*>(&e_s[d][2 * tyc]);
            acc[0][0] += xa.x * ev.x; acc[0][1] += xa.x * ev.y;
            acc[1][0] += xa.y * ev.x; acc[1][1] += xa.y * ev.y;
            acc[2][0] += xa.z * ev.x; acc[2][1] += xa.z * ev.y;
            acc[3][0] += xa.w * ev.x; acc[3][1] += xa.w * ev.y;
            acc[4][0] += xb.x * ev.x; acc[4][1] += xb.x * ev.y;
            acc[5][0] += xb.y * ev.x; acc[5][1] += xb.y * ev.y;
            acc[6][0] += xb.z * ev.x; acc[6][1] += xb.z * ev.y;
            acc[7][0] += xb.w * ev.x; acc[7][1] += xb.w * ev.y;
        }

        // ---- argmin update (||x||^2 dropped: constant per row) ----
        const float en0 = enorm[kbase + 2 * tyc];
        const float en1 = enorm[kbase + 2 * tyc + 1];
        const int k0 = kbase + 2 * tyc;
#pragma unroll
        for (int i = 0; i < 8; ++i) {
            float d0 = en0 - 2.f * acc[i][0];
            if (d0 < bestd[i]) { bestd[i] = d0; bestk[i] = k0; }
            float d1 = en1 - 2.f * acc[i][1];
            if (d1 < bestd[i]) { bestd[i] = d1; bestk[i] = k0 + 1; }
        }

        // ---- fused zero-fill of one-hot for this chunk's columns ----
#pragma unroll
        for (int j = 0; j < (RT * CT / 4) / THREADS; ++j) {  // 4
            int h = t + THREADS * j;
            int row = h >> 5;
            int c4 = (h & 31) << 2;
            float4 z; z.x = 0.f; z.y = 0.f; z.z = 0.f; z.w = 0.f;
            *reinterpret_cast<float4*>(&enc[(size_t)(brow + row) * K + kbase + c4]) = z;
        }
    }

    __syncthreads();
    // Overlay scratch onto e_s (free after chunk loop)
    float* cd = &e_s[0][0];                                       // [64][32]
    int* ck = reinterpret_cast<int*>(&e_s[0][0]) + 64 * 32;       // [64][32]
    int* sbk = reinterpret_cast<int*>(&e_s[0][0]) + 2 * 64 * 32;  // [32]
    float* red = &e_s[0][0] + 2 * 64 * 32 + 32;                   // [256]

#pragma unroll
    for (int i = 0; i < 8; ++i) {
        cd[tyc * 32 + 8 * txr + i] = bestd[i];
        ck[tyc * 32 + 8 * txr + i] = bestk[i];
    }
    __syncthreads();

    if (t < RT) {
        const int r = t;
        float bd = cd[r];
        int bk = ck[r];
        for (int g = 1; g < 64; ++g) {
            float dv = cd[g * 32 + r];
            int kv = ck[g * 32 + r];
            if (dv < bd || (dv == bd && kv < bk)) { bd = dv; bk = kv; }
        }
        idxout[brow + r] = (float)bk;
        enc[(size_t)(brow + r) * K + bk] = 1.0f;   // zero was written pre-barrier
        sbk[r] = bk;
    }
    __syncthreads();

    // ---- quantized + loss partial ----
    const int r = t >> 3;   // 0..31
    const int s = t & 7;    // 0..7
    const int bk = sbk[r];
    float part = 0.f;
#pragma unroll
    for (int j = 0; j < 16; ++j) {
        int d = s + 8 * j;
        float xv = x_s[d][r];
        float ev = E[(size_t)d * K + bk];
        float qv = xv + (ev - xv);   // straight-through, matches reference arithmetic
        qout[(size_t)(brow + r) * D + d] = qv;
        float df = ev - xv;
        part += df * df;
    }
    red[t] = part;
    __syncthreads();
#pragma unroll
    for (int off = 128; off > 0; off >>= 1) {
        if (t < off) red[t] += red[t + off];
        __syncthreads();
    }
    if (t == 0) partials[bid] = red[0];
}

__global__ __launch_bounds__(256) void loss_kernel(const float* __restrict__ partials,
                                                   float* __restrict__ out) {
    __shared__ float red[256];
    const int t = threadIdx.x;
    red[t] = partials[t] + partials[t + 256];
    __syncthreads();
#pragma unroll
    for (int off = 128; off > 0; off >>= 1) {
        if (t < off) red[t] += red[t + off];
        __syncthreads();
    }
    if (t == 0) {
        float mean = red[0] / (float)((size_t)N * D);
        out[(size_t)N * D + (size_t)N * K + N] = mean + 0.25f * mean;
    }
}

extern "C" void kernel_launch(void* const* d_in, const int* in_sizes, int n_in,
                              void* d_out, int out_size, void* d_ws, size_t ws_size,
                              hipStream_t stream) {
    const float* X = (const float*)d_in[0];
    const float* E = (const float*)d_in[1];
    float* out = (float*)d_out;
    float* enorm = (float*)d_ws;              // 8192 f32
    float* partials = enorm + K;              // 512 f32

    hipLaunchKernelGGL(enorm_kernel, dim3(K / 256), dim3(256), 0, stream, E, enorm);
    hipLaunchKernelGGL(main_kernel, dim3(MAIN_BLOCKS), dim3(THREADS), 0, stream,
                       X, E, enorm, out, partials);
    hipLaunchKernelGGL(loss_kernel, dim3(1), dim3(256), 0, stream, partials, out);
}

// Round 3
// 223.975 us; speedup vs baseline: 2.8010x; 2.8010x over previous
//
#include <hip/hip_runtime.h>

// VectorQuantizer: X [16384][128] f32, E [128][8192] f32
// out (f32 flat): quantized [16384*128], encodings [16384*8192], indices [16384], loss [1]
#define D 128
#define K 8192
#define N 16384
#define BM 128                // rows per pass-block
#define BN 256                // cols per chunk
#define NCOLG 2
#define COLG (K / NCOLG)      // 4096
#define NCH (COLG / BN)       // 16
#define THREADS 512
#define CAND_CAP 4096
#define DELTA 0.5f

typedef __attribute__((ext_vector_type(4))) float f32x4;
typedef __attribute__((ext_vector_type(16))) float f32x16;
typedef __attribute__((ext_vector_type(8))) short short8;

__device__ __forceinline__ unsigned short f2bf(float f) {
    unsigned int b = __float_as_uint(f);
    return (unsigned short)((b + 0x7FFFu + ((b >> 16) & 1u)) >> 16);
}
__device__ __forceinline__ unsigned int fsort(float f) {
    unsigned int b = __float_as_uint(f);
    return b ^ ((unsigned int)((int)b >> 31) | 0x80000000u);
}
__device__ __forceinline__ float funsort(unsigned int u) {
    return __uint_as_float((u & 0x80000000u) ? (u ^ 0x80000000u) : ~u);
}

// ---- prep: E -> bf16 transposed [k][d], enorm f32, init ws reducers ----
__global__ __launch_bounds__(256) void prep_kernel(const float* __restrict__ E,
        unsigned short* __restrict__ e1t, float* __restrict__ enorm,
        unsigned int* __restrict__ mws, unsigned long long* __restrict__ bestws) {
    __shared__ float esum[8][32];
    const int t = threadIdx.x;
    const int kl = t & 31, dg = t >> 5;
    const int k = blockIdx.x * 32 + kl;
    float s = 0.f;
    __align__(16) unsigned short tmp[16];
#pragma unroll
    for (int j = 0; j < 16; ++j) {
        float v = E[(size_t)(dg * 16 + j) * K + k];
        s += v * v;
        tmp[j] = f2bf(v);
    }
    *(f32x4*)(e1t + (size_t)k * D + dg * 16) = *(const f32x4*)tmp;
    *(f32x4*)(e1t + (size_t)k * D + dg * 16 + 8) = *(const f32x4*)(tmp + 8);
    esum[dg][kl] = s;
    __syncthreads();
    if (t < 32) {
        float e = 0.f;
#pragma unroll
        for (int g = 0; g < 8; ++g) e += esum[g][t];
        enorm[blockIdx.x * 32 + t] = e;
    }
    if (t < 64) {
        int r = blockIdx.x * 64 + t;
        mws[r] = 0xFFFFFFFFu;
        bestws[r] = ~0ull;
    }
}

// ---- pass kernel: bf16 MFMA approx distances ----
// PASS 0: per-row approx min -> mws. PASS 1: candidates -> exact f32 -> bestws.
// Both: zero-fill half of the one-hot output (chunk parity == PASS).
template<int PASS>
__global__ __launch_bounds__(THREADS, 2) void pass_kernel(
        const float* __restrict__ X, const float* __restrict__ E,
        const unsigned short* __restrict__ e1t, const float* __restrict__ enorm,
        float* __restrict__ enc, unsigned int* __restrict__ mws,
        unsigned long long* __restrict__ bestws) {
    __shared__ __align__(16) unsigned short b_s[2][BN * D];  // 2 x 64 KB, XOR-swizzled
    __shared__ unsigned int cand[CAND_CAP];
    __shared__ float thr_s[BM];
    __shared__ int candn;

    const int t = threadIdx.x;
    const int wid = t >> 6, l = t & 63;
    const int l31 = l & 31, lh = l >> 5;
    const int mblk = blockIdx.x >> 1, cg = blockIdx.x & 1;
    const int rowbase = mblk * BM;
    const int colg = cg * COLG;
    const int wm = wid >> 2, wn = wid & 3;

    if (PASS == 1) {
        if (t < BM) thr_s[t] = funsort(mws[rowbase + t]) + DELTA;
        if (t == 0) candn = 0;
    }

    // A fragments resident in registers: rows rowbase + wm*64 + mf*32 + l31
    short8 afr[2][8];
#pragma unroll
    for (int mf = 0; mf < 2; ++mf) {
        const int row = rowbase + wm * 64 + mf * 32 + l31;
#pragma unroll
        for (int ks = 0; ks < 8; ++ks) {
            const float* xp = X + (size_t)row * D + ks * 16 + lh * 8;
            f32x4 v0 = *(const f32x4*)xp;
            f32x4 v1 = *(const f32x4*)(xp + 4);
            short8 a;
            a[0] = (short)f2bf(v0[0]); a[1] = (short)f2bf(v0[1]);
            a[2] = (short)f2bf(v0[2]); a[3] = (short)f2bf(v0[3]);
            a[4] = (short)f2bf(v1[0]); a[5] = (short)f2bf(v1[1]);
            a[6] = (short)f2bf(v1[2]); a[7] = (short)f2bf(v1[3]);
            afr[mf][ks] = a;
        }
    }

    float minv0[16], minv1[16];
    if (PASS == 0) {
#pragma unroll
        for (int r = 0; r < 16; ++r) { minv0[r] = 1e30f; minv1[r] = 1e30f; }
    }

    f32x4 sreg[8];
    {   // prologue: stage chunk 0 into buf 0 (linear global read, swizzled LDS write)
        const f32x4* gs = (const f32x4*)(e1t + (size_t)colg * D);
#pragma unroll
        for (int i = 0; i < 8; ++i) sreg[i] = gs[t + THREADS * i];
#pragma unroll
        for (int i = 0; i < 8; ++i) {
            int unit = t + THREADS * i;
            int c = unit >> 4, slot = unit & 15;
            *(f32x4*)((char*)&b_s[0][0] + c * 256 + ((slot ^ (c & 15)) << 4)) = sreg[i];
        }
    }

    int cur = 0;
    for (int ch = 0; ch < NCH; ++ch) {
        if (ch + 1 < NCH) {  // issue next-chunk global loads early
            const f32x4* gs = (const f32x4*)(e1t + (size_t)(colg + (ch + 1) * BN) * D);
#pragma unroll
            for (int i = 0; i < 8; ++i) sreg[i] = gs[t + THREADS * i];
        }
        __syncthreads();   // b_s[cur] ready; previous readers done

        f32x16 acc[2][2];
#pragma unroll
        for (int mf = 0; mf < 2; ++mf)
#pragma unroll
            for (int nf = 0; nf < 2; ++nf)
#pragma unroll
                for (int r = 0; r < 16; ++r) acc[mf][nf][r] = 0.f;

#pragma unroll
        for (int ks = 0; ks < 8; ++ks) {
            short8 bf[2];
#pragma unroll
            for (int nf = 0; nf < 2; ++nf) {
                int c = wn * 64 + nf * 32 + l31;
                int slot = ks * 2 + lh;
                bf[nf] = *(const short8*)((const char*)&b_s[cur][0] + c * 256 + ((slot ^ (c & 15)) << 4));
            }
#pragma unroll
            for (int mf = 0; mf < 2; ++mf)
#pragma unroll
                for (int nf = 0; nf < 2; ++nf)
                    acc[mf][nf] = __builtin_amdgcn_mfma_f32_32x32x16_bf16(
                        afr[mf][ks], bf[nf], acc[mf][nf], 0, 0, 0);
        }

        const int chcol = colg + ch * BN;
#pragma unroll
        for (int nf = 0; nf < 2; ++nf) {
            const int col = chcol + wn * 64 + nf * 32 + l31;
            const float en = enorm[col];
#pragma unroll
            for (int mf = 0; mf < 2; ++mf) {
#pragma unroll
                for (int r = 0; r < 16; ++r) {
                    float dt = en - 2.f * acc[mf][nf][r];
                    if (PASS == 0) {
                        if (mf == 0) minv0[r] = fminf(minv0[r], dt);
                        else         minv1[r] = fminf(minv1[r], dt);
                    } else {
                        const int ro = wm * 64 + mf * 32 + (r & 3) + 8 * (r >> 2) + 4 * lh;
                        if (dt < thr_s[ro]) {
                            int idx = atomicAdd(&candn, 1);
                            if (idx < CAND_CAP) cand[idx] = ((unsigned)ro << 13) | (unsigned)col;
                        }
                    }
                }
            }
        }

        // fused one-hot zero-fill: this pass covers chunks with matching parity
        if (((cg * NCH + ch) & 1) == PASS) {
            const f32x4 z = {0.f, 0.f, 0.f, 0.f};
#pragma unroll
            for (int i = 0; i < 16; ++i) {
                int unit = t + THREADS * i;
                int row = unit >> 6, cu = unit & 63;
                *(f32x4*)(enc + (size_t)(rowbase + row) * K + chcol + cu * 4) = z;
            }
        }

        if (ch + 1 < NCH) {  // write next chunk into the other buffer
#pragma unroll
            for (int i = 0; i < 8; ++i) {
                int unit = t + THREADS * i;
                int c = unit >> 4, slot = unit & 15;
                *(f32x4*)((char*)&b_s[cur ^ 1][0] + c * 256 + ((slot ^ (c & 15)) << 4)) = sreg[i];
            }
        }
        cur ^= 1;
    }

    if (PASS == 0) {
        // reduce per-row min over the 32 col-lanes, push to ws
#pragma unroll
        for (int r = 0; r < 16; ++r) {
#pragma unroll
            for (int m = 1; m <= 16; m <<= 1) {
                minv0[r] = fminf(minv0[r], __shfl_xor(minv0[r], m, 64));
                minv1[r] = fminf(minv1[r], __shfl_xor(minv1[r], m, 64));
            }
        }
        if (l31 == 0) {
#pragma unroll
            for (int r = 0; r < 16; ++r) {
                int roff = (r & 3) + 8 * (r >> 2) + 4 * lh;
                atomicMin(&mws[rowbase + wm * 64 + roff], fsort(minv0[r]));
                atomicMin(&mws[rowbase + wm * 64 + 32 + roff], fsort(minv1[r]));
            }
        }
    } else {
        __syncthreads();
        int n = candn; if (n > CAND_CAP) n = CAND_CAP;
        for (int i = wid; i < n; i += 8) {   // one wave per candidate
            unsigned int pc = cand[i];
            int ro = pc >> 13, col = pc & 8191;
            const float* xr = X + (size_t)(rowbase + ro) * D;
            float x0 = xr[l], x1 = xr[l + 64];
            float e0 = E[(size_t)l * K + col], e1 = E[(size_t)(l + 64) * K + col];
            float s = x0 * e0 + x1 * e1;
#pragma unroll
            for (int m = 1; m <= 32; m <<= 1) s += __shfl_xor(s, m, 64);
            if (l == 0) {
                float dtx = enorm[col] - 2.f * s;
                unsigned long long pk = ((unsigned long long)fsort(dtx) << 32) | (unsigned)col;
                atomicMin(&bestws[rowbase + ro], pk);
            }
        }
    }
}

// ---- final: indices, one-hot scatter, quantized, loss partials ----
__global__ __launch_bounds__(256) void final_kernel(const float* __restrict__ X,
        const float* __restrict__ E, const unsigned long long* __restrict__ bestws,
        float* __restrict__ out, float* __restrict__ partials) {
    const int t = threadIdx.x;
    const int rl = t >> 4, s = t & 15;
    const int row = blockIdx.x * 16 + rl;
    float* qout = out;
    float* enc = out + (size_t)N * D;
    float* idxout = enc + (size_t)N * K;
    const int k = (int)(bestws[row] & 8191ull);
    const float* xp = X + (size_t)row * D + s * 8;
    f32x4 xv0 = *(const f32x4*)xp;
    f32x4 xv1 = *(const f32x4*)(xp + 4);
    f32x4 q0, q1;
    float part = 0.f;
#pragma unroll
    for (int j = 0; j < 4; ++j) {
        float e0 = E[(size_t)(s * 8 + j) * K + k];
        float d0 = e0 - xv0[j];
        q0[j] = xv0[j] + d0; part += d0 * d0;
        float e1 = E[(size_t)(s * 8 + 4 + j) * K + k];
        float d1 = e1 - xv1[j];
        q1[j] = xv1[j] + d1; part += d1 * d1;
    }
    *(f32x4*)(qout + (size_t)row * D + s * 8) = q0;
    *(f32x4*)(qout + (size_t)row * D + s * 8 + 4) = q1;
#pragma unroll
    for (int m = 1; m <= 8; m <<= 1) part += __shfl_xor(part, m, 64);
    __shared__ float rr[16];
    if (s == 0) {
        idxout[row] = (float)k;
        enc[(size_t)row * K + k] = 1.0f;
        rr[rl] = part;
    }
    __syncthreads();
    if (t == 0) {
        float sum = 0.f;
#pragma unroll
        for (int i = 0; i < 16; ++i) sum += rr[i];
        partials[blockIdx.x] = sum;
    }
}

__global__ __launch_bounds__(256) void loss_kernel(const float* __restrict__ partials,
                                                   float* __restrict__ out) {
    __shared__ float red[256];
    const int t = threadIdx.x;
    red[t] = partials[t] + partials[t + 256] + partials[t + 512] + partials[t + 768];
    __syncthreads();
    for (int off = 128; off > 0; off >>= 1) {
        if (t < off) red[t] += red[t + off];
        __syncthreads();
    }
    if (t == 0) {
        float mean = red[0] / (float)((size_t)N * D);
        out[(size_t)N * D + (size_t)N * K + N] = mean + 0.25f * mean;
    }
}

extern "C" void kernel_launch(void* const* d_in, const int* in_sizes, int n_in,
                              void* d_out, int out_size, void* d_ws, size_t ws_size,
                              hipStream_t stream) {
    const float* X = (const float*)d_in[0];
    const float* E = (const float*)d_in[1];
    float* out = (float*)d_out;
    char* ws = (char*)d_ws;
    unsigned short* e1t = (unsigned short*)ws;                                    // 2 MB
    float* enorm = (float*)(ws + 2u * 1024 * 1024);                               // 32 KB
    unsigned int* mws = (unsigned int*)(ws + 2u * 1024 * 1024 + 32 * 1024);       // 64 KB
    unsigned long long* bestws =
        (unsigned long long*)(ws + 2u * 1024 * 1024 + 96 * 1024);                 // 128 KB
    float* partials = (float*)(ws + 2u * 1024 * 1024 + 224 * 1024);               // 4 KB
    float* enc = out + (size_t)N * D;

    hipLaunchKernelGGL(prep_kernel, dim3(K / 32), dim3(256), 0, stream,
                       E, e1t, enorm, mws, bestws);
    hipLaunchKernelGGL((pass_kernel<0>), dim3(256), dim3(THREADS), 0, stream,
                       X, E, e1t, enorm, enc, mws, bestws);
    hipLaunchKernelGGL((pass_kernel<1>), dim3(256), dim3(THREADS), 0, stream,
                       X, E, e1t, enorm, enc, mws, bestws);
    hipLaunchKernelGGL(final_kernel, dim3(N / 16), dim3(256), 0, stream,
                       X, E, bestws, out, partials);
    hipLaunchKernelGGL(loss_kernel, dim3(1), dim3(256), 0, stream, partials, out);
}

// Round 5
// 200.521 us; speedup vs baseline: 3.1286x; 1.1170x over previous
//
#include <hip/hip_runtime.h>

// VectorQuantizer: X [16384][128] f32, E [128][8192] f32
// out (f32 flat): quantized [16384*128], encodings [16384*8192], indices [16384], loss [1]
#define D 128
#define K 8192
#define N 16384
#define BM 64                 // rows per block
#define BN 256                // codebook cols per chunk
#define NCH (K / BN)          // 32
#define THREADS 512
#define CAND_CAP 3072
#define DELTA 0.5f
#define RMIN_INIT 0xFF800000u // fsort(+inf) -> funsort gives +inf (NOT 0xFFFFFFFF: that decodes to NaN)

typedef __attribute__((ext_vector_type(4))) float f32x4;
typedef __attribute__((ext_vector_type(16))) float f32x16;
typedef __attribute__((ext_vector_type(8))) short short8;

__device__ __forceinline__ unsigned short f2bf(float f) {
    unsigned int b = __float_as_uint(f);
    return (unsigned short)((b + 0x7FFFu + ((b >> 16) & 1u)) >> 16);
}
__device__ __forceinline__ unsigned int fsort(float f) {
    unsigned int b = __float_as_uint(f);
    return b ^ ((unsigned int)((int)b >> 31) | 0x80000000u);
}
__device__ __forceinline__ float funsort(unsigned int u) {
    return __uint_as_float((u & 0x80000000u) ? (u ^ 0x80000000u) : ~u);
}

// ---- prep: E -> bf16 transposed e1t[k][d], f32 transposed e2t[k][d], enorm ----
__global__ __launch_bounds__(256) void prep_kernel(const float* __restrict__ E,
        unsigned short* __restrict__ e1t, float* __restrict__ e2t,
        float* __restrict__ enorm) {
    __shared__ float esum[8][32];
    const int t = threadIdx.x;
    const int kl = t & 31, dg = t >> 5;
    const int k = blockIdx.x * 32 + kl;
    float s = 0.f;
    __align__(16) unsigned short tmpb[16];
    __align__(16) float tmpf[16];
#pragma unroll
    for (int j = 0; j < 16; ++j) {
        float v = E[(size_t)(dg * 16 + j) * K + k];
        s += v * v;
        tmpb[j] = f2bf(v);
        tmpf[j] = v;
    }
    *(f32x4*)(e1t + (size_t)k * D + dg * 16) = *(const f32x4*)tmpb;
    *(f32x4*)(e1t + (size_t)k * D + dg * 16 + 8) = *(const f32x4*)(tmpb + 8);
    if (e2t) {
#pragma unroll
        for (int q = 0; q < 4; ++q)
            *(f32x4*)(e2t + (size_t)k * D + dg * 16 + 4 * q) = *(const f32x4*)(tmpf + 4 * q);
    }
    esum[dg][kl] = s;
    __syncthreads();
    if (t < 32) {
        float e = 0.f;
#pragma unroll
        for (int g = 0; g < 8; ++g) e += esum[g][t];
        enorm[blockIdx.x * 32 + t] = e;
    }
}

// ---- main: one sweep (MFMA approx dists + wave-min-gated candidate capture +
//      fused one-hot zero-fill), then exact f32 verify, then all outputs ----
template<int E2T>
__global__ __launch_bounds__(THREADS, 2) void main_kernel(
        const float* __restrict__ X, const float* __restrict__ E,
        const unsigned short* __restrict__ e1t, const float* __restrict__ e2t,
        const float* __restrict__ enorm, float* __restrict__ out,
        float* __restrict__ partials) {
    __shared__ __align__(16) unsigned short b_s[2][BN * D];      // 128 KB, XOR-swizzled
    __shared__ unsigned long long cand[CAND_CAP];                // 24 KB
    __shared__ unsigned long long best[BM];                      // 512 B
    __shared__ unsigned int rmin[BM];                            // 256 B
    __shared__ float red[THREADS];                               // 2 KB
    __shared__ int candn;

    const int t = threadIdx.x;
    const int wid = t >> 6, l = t & 63;
    const int l31 = l & 31, lh = l >> 5;
    const int wm = wid >> 2, wn = wid & 3;
    const int rowbase = blockIdx.x * BM;

    float* qout = out;
    float* enc = out + (size_t)N * D;
    float* idxout = enc + (size_t)N * K;

    if (t < BM) { rmin[t] = RMIN_INIT; best[t] = ~0ull; }
    if (t == 0) candn = 0;

    // A fragments: wave's 32 rows = rowbase + wm*32 + l31
    short8 afr[8];
    {
        const int row = rowbase + wm * 32 + l31;
#pragma unroll
        for (int ks = 0; ks < 8; ++ks) {
            const float* xp = X + (size_t)row * D + ks * 16 + lh * 8;
            f32x4 v0 = *(const f32x4*)xp;
            f32x4 v1 = *(const f32x4*)(xp + 4);
            short8 a;
            a[0] = (short)f2bf(v0[0]); a[1] = (short)f2bf(v0[1]);
            a[2] = (short)f2bf(v0[2]); a[3] = (short)f2bf(v0[3]);
            a[4] = (short)f2bf(v1[0]); a[5] = (short)f2bf(v1[1]);
            a[6] = (short)f2bf(v1[2]); a[7] = (short)f2bf(v1[3]);
            afr[ks] = a;
        }
    }

    f32x4 sreg[8];
    {   // prologue: stage chunk 0 into buf 0
        const f32x4* gs = (const f32x4*)e1t;
#pragma unroll
        for (int i = 0; i < 8; ++i) sreg[i] = gs[t + THREADS * i];
#pragma unroll
        for (int i = 0; i < 8; ++i) {
            int unit = t + THREADS * i;
            int c = unit >> 4, slot = unit & 15;
            *(f32x4*)((char*)&b_s[0][0] + c * 256 + ((slot ^ (c & 15)) << 4)) = sreg[i];
        }
    }

    int cur = 0;
    for (int ch = 0; ch < NCH; ++ch) {
        if (ch + 1 < NCH) {
            const f32x4* gs = (const f32x4*)(e1t + (size_t)(ch + 1) * BN * D);
#pragma unroll
            for (int i = 0; i < 8; ++i) sreg[i] = gs[t + THREADS * i];
        }
        __syncthreads();   // buf[cur] ready; rmin updates of prev chunk visible

        // per-row threshold cache (stale-safe: any observed value >= final)
        float thrv[16];
#pragma unroll
        for (int q = 0; q < 4; ++q) {
            const int base = wm * 32 + 4 * lh + 8 * q;
            uint4 rv = *(const uint4*)&rmin[base];
            thrv[4 * q + 0] = funsort(rv.x);
            thrv[4 * q + 1] = funsort(rv.y);
            thrv[4 * q + 2] = funsort(rv.z);
            thrv[4 * q + 3] = funsort(rv.w);
        }

        f32x16 acc[2];
#pragma unroll
        for (int nf = 0; nf < 2; ++nf)
#pragma unroll
            for (int r = 0; r < 16; ++r) acc[nf][r] = 0.f;

#pragma unroll
        for (int ks = 0; ks < 8; ++ks) {
            short8 bf[2];
#pragma unroll
            for (int nf = 0; nf < 2; ++nf) {
                int c = wn * 64 + nf * 32 + l31;
                int slot = ks * 2 + lh;
                bf[nf] = *(const short8*)((const char*)&b_s[cur][0] + c * 256 + ((slot ^ (c & 15)) << 4));
            }
#pragma unroll
            for (int nf = 0; nf < 2; ++nf)
                acc[nf] = __builtin_amdgcn_mfma_f32_32x32x16_bf16(afr[ks], bf[nf], acc[nf], 0, 0, 0);
        }

        const int chcol = ch * BN;
        float dts[2][16];
#pragma unroll
        for (int nf = 0; nf < 2; ++nf) {
            const int col = chcol + wn * 64 + nf * 32 + l31;
            const float en = enorm[col];
#pragma unroll
            for (int r = 0; r < 16; ++r) dts[nf][r] = en - 2.f * acc[nf][r];
        }

        // wave-level per-row-slot min over this chunk's 64 cols (tightens the
        // push gate BEFORE any push -> no candidate flooding in early chunks)
        float cmin[16];
#pragma unroll
        for (int r = 0; r < 16; ++r) cmin[r] = fminf(dts[0][r], dts[1][r]);
#pragma unroll
        for (int m = 1; m <= 16; m <<= 1)
#pragma unroll
            for (int r = 0; r < 16; ++r)
                cmin[r] = fminf(cmin[r], __shfl_xor(cmin[r], m, 64));

#pragma unroll
        for (int r = 0; r < 16; ++r) {
            const int ro = wm * 32 + 4 * lh + 8 * (r >> 2) + (r & 3);
            const float te = fminf(thrv[r], cmin[r]) + DELTA;
#pragma unroll
            for (int nf = 0; nf < 2; ++nf) {
                if (dts[nf][r] < te) {
                    const int col = chcol + wn * 64 + nf * 32 + l31;
                    int ci = atomicAdd(&candn, 1);
                    if (ci < CAND_CAP)
                        cand[ci] = ((unsigned long long)fsort(dts[nf][r]) << 32) |
                                   ((unsigned long long)ro << 13) | (unsigned)col;
                }
            }
            if (l31 == 0 && cmin[r] < thrv[r])
                atomicMin(&rmin[ro], fsort(cmin[r]));
        }

        // fused one-hot zero-fill for this chunk's 64 rows x 256 cols (nontemporal)
        {
            const f32x4 z = {0.f, 0.f, 0.f, 0.f};
#pragma unroll
            for (int i = 0; i < 8; ++i) {
                int unit = t + THREADS * i;
                int row = unit >> 6, cu = unit & 63;
                __builtin_nontemporal_store(z,
                    (f32x4*)(enc + (size_t)(rowbase + row) * K + chcol + cu * 4));
            }
        }

        if (ch + 1 < NCH) {
#pragma unroll
            for (int i = 0; i < 8; ++i) {
                int unit = t + THREADS * i;
                int c = unit >> 4, slot = unit & 15;
                *(f32x4*)((char*)&b_s[cur ^ 1][0] + c * 256 + ((slot ^ (c & 15)) << 4)) = sreg[i];
            }
        }
        cur ^= 1;
    }

    __syncthreads();   // rmin/cand final; zero-fill stores drained

    // ---- exact f32 verification of surviving candidates ----
    {
        int n = candn; if (n > CAND_CAP) n = CAND_CAP;
        for (int i = wid; i < n; i += 8) {     // one wave per candidate
            const unsigned long long e = cand[i];
            const float dta = funsort((unsigned int)(e >> 32));
            const int ro = (int)((e >> 13) & 63u);
            const int col = (int)(e & 8191u);
            if (dta < funsort(rmin[ro]) + DELTA) {
                const int row = rowbase + ro;
                float x0 = X[(size_t)row * D + l];
                float x1 = X[(size_t)row * D + 64 + l];
                float e0, e1;
                if (E2T) {
                    e0 = e2t[(size_t)col * D + l];
                    e1 = e2t[(size_t)col * D + 64 + l];
                } else {
                    e0 = E[(size_t)l * K + col];
                    e1 = E[(size_t)(l + 64) * K + col];
                }
                float s = x0 * e0 + x1 * e1;
#pragma unroll
                for (int m = 1; m <= 32; m <<= 1) s += __shfl_xor(s, m, 64);
                if (l == 0) {
                    float dtx = enorm[col] - 2.f * s;
                    atomicMin(&best[ro],
                        ((unsigned long long)fsort(dtx) << 32) | (unsigned)col);
                }
            }
        }
    }
    __syncthreads();

    // ---- outputs: indices, one-hot scatter, quantized, loss partial ----
    if (t < BM) {
        const int k = (int)(best[t] & 8191ull);
        idxout[rowbase + t] = (float)k;
        __builtin_nontemporal_store(1.0f, &enc[(size_t)(rowbase + t) * K + k]);
    }

    const int rr = t >> 3, sL = t & 7;
    const int row = rowbase + rr;
    const int kb = (int)(best[rr] & 8191ull);
    float part = 0.f;
#pragma unroll
    for (int j = 0; j < 4; ++j) {
        const int d0 = sL * 16 + 4 * j;
        f32x4 xv = *(const f32x4*)(X + (size_t)row * D + d0);
        f32x4 ev;
        if (E2T) {
            ev = *(const f32x4*)(e2t + (size_t)kb * D + d0);
        } else {
#pragma unroll
            for (int u = 0; u < 4; ++u) ev[u] = E[(size_t)(d0 + u) * K + kb];
        }
        f32x4 qv;
#pragma unroll
        for (int u = 0; u < 4; ++u) {
            float df = ev[u] - xv[u];
            qv[u] = xv[u] + df;
            part += df * df;
        }
        *(f32x4*)(qout + (size_t)row * D + d0) = qv;
    }
    red[t] = part;
    __syncthreads();
#pragma unroll
    for (int off = THREADS / 2; off > 0; off >>= 1) {
        if (t < off) red[t] += red[t + off];
        __syncthreads();
    }
    if (t == 0) partials[blockIdx.x] = red[0];
}

__global__ __launch_bounds__(256) void loss_kernel(const float* __restrict__ partials,
                                                   float* __restrict__ out) {
    __shared__ float red[256];
    const int t = threadIdx.x;
    red[t] = partials[t];
    __syncthreads();
    for (int off = 128; off > 0; off >>= 1) {
        if (t < off) red[t] += red[t + off];
        __syncthreads();
    }
    if (t == 0) {
        float mean = red[0] / (float)((size_t)N * D);
        out[(size_t)N * D + (size_t)N * K + N] = mean + 0.25f * mean;
    }
}

extern "C" void kernel_launch(void* const* d_in, const int* in_sizes, int n_in,
                              void* d_out, int out_size, void* d_ws, size_t ws_size,
                              hipStream_t stream) {
    const float* X = (const float*)d_in[0];
    const float* E = (const float*)d_in[1];
    float* out = (float*)d_out;
    char* ws = (char*)d_ws;

    const size_t E1T_B = (size_t)K * D * 2;          // 2 MB
    const size_t E2T_B = (size_t)K * D * 4;          // 4 MB
    const bool use_e2t = ws_size >= E1T_B + E2T_B + 64 * 1024;

    unsigned short* e1t = (unsigned short*)ws;
    float* e2t; float* enorm; float* partials;
    if (use_e2t) {
        e2t = (float*)(ws + E1T_B);
        enorm = (float*)(ws + E1T_B + E2T_B);
        partials = enorm + K;
    } else {
        e2t = nullptr;
        enorm = (float*)(ws + E1T_B);
        partials = enorm + K;
    }

    hipLaunchKernelGGL(prep_kernel, dim3(K / 32), dim3(256), 0, stream,
                       E, e1t, e2t, enorm);
    if (use_e2t)
        hipLaunchKernelGGL((main_kernel<1>), dim3(N / BM), dim3(THREADS), 0, stream,
                           X, E, e1t, e2t, enorm, out, partials);
    else
        hipLaunchKernelGGL((main_kernel<0>), dim3(N / BM), dim3(THREADS), 0, stream,
                           X, E, e1t, e2t, enorm, out, partials);
    hipLaunchKernelGGL(loss_kernel, dim3(1), dim3(256), 0, stream, partials, out);
}

// Round 7
// 187.980 us; speedup vs baseline: 3.3373x; 1.0667x over previous
//
#include <hip/hip_runtime.h>

// VectorQuantizer: X [16384][128] f32, E [128][8192] f32
// out (f32 flat): quantized [16384*128], encodings [16384*8192], indices [16384], loss [1]
#define D 128
#define K 8192
#define N 16384
#define BM 64                 // rows per block
#define BN 256                // codebook cols per chunk
#define NCH (K / BN)          // 32
#define THREADS 512
#define CAND_CAP 3072
#define DELTA 0.5f
#define RMIN_INIT 0xFF800000u // fsort(+inf) -> funsort gives +inf (NOT 0xFFFFFFFF: that decodes to NaN)

typedef __attribute__((ext_vector_type(4))) float f32x4;
typedef __attribute__((ext_vector_type(16))) float f32x16;
typedef __attribute__((ext_vector_type(8))) short short8;

__device__ __forceinline__ unsigned short f2bf(float f) {
    unsigned int b = __float_as_uint(f);
    return (unsigned short)((b + 0x7FFFu + ((b >> 16) & 1u)) >> 16);
}
__device__ __forceinline__ unsigned int fsort(float f) {
    unsigned int b = __float_as_uint(f);
    return b ^ ((unsigned int)((int)b >> 31) | 0x80000000u);
}
__device__ __forceinline__ float funsort(unsigned int u) {
    return __uint_as_float((u & 0x80000000u) ? (u ^ 0x80000000u) : ~u);
}

// LDS-only barrier: each thread waits for ITS LDS ops (writes, reads, atomics),
// then syncs. Global loads/stores stay in flight across chunks — the in-loop
// __syncthreads()'s vmcnt(0) drain of the 64KB/chunk zero-fill stores was the
// R5 bottleneck (serialized store completion with compute at 1 block/CU).
__device__ __forceinline__ void lds_barrier() {
    asm volatile("s_waitcnt lgkmcnt(0)" ::: "memory");
    __builtin_amdgcn_s_barrier();
}

// ---- prep: E -> bf16 transposed e1t[k][d], f32 transposed e2t[k][d], enorm ----
__global__ __launch_bounds__(256) void prep_kernel(const float* __restrict__ E,
        unsigned short* __restrict__ e1t, float* __restrict__ e2t,
        float* __restrict__ enorm) {
    __shared__ float esum[8][32];
    const int t = threadIdx.x;
    const int kl = t & 31, dg = t >> 5;
    const int k = blockIdx.x * 32 + kl;
    float s = 0.f;
    __align__(16) unsigned short tmpb[16];
    __align__(16) float tmpf[16];
#pragma unroll
    for (int j = 0; j < 16; ++j) {
        float v = E[(size_t)(dg * 16 + j) * K + k];
        s += v * v;
        tmpb[j] = f2bf(v);
        tmpf[j] = v;
    }
    *(f32x4*)(e1t + (size_t)k * D + dg * 16) = *(const f32x4*)tmpb;
    *(f32x4*)(e1t + (size_t)k * D + dg * 16 + 8) = *(const f32x4*)(tmpb + 8);
    if (e2t) {
#pragma unroll
        for (int q = 0; q < 4; ++q)
            *(f32x4*)(e2t + (size_t)k * D + dg * 16 + 4 * q) = *(const f32x4*)(tmpf + 4 * q);
    }
    esum[dg][kl] = s;
    __syncthreads();
    if (t < 32) {
        float e = 0.f;
#pragma unroll
        for (int g = 0; g < 8; ++g) e += esum[g][t];
        enorm[blockIdx.x * 32 + t] = e;
    }
}

// ---- main: one sweep (MFMA approx dists + wave-min-gated candidate capture +
//      fused one-hot zero-fill), then exact f32 verify, then all outputs ----
template<int E2T>
__global__ __launch_bounds__(THREADS, 2) void main_kernel(
        const float* __restrict__ X, const float* __restrict__ E,
        const unsigned short* __restrict__ e1t, const float* __restrict__ e2t,
        const float* __restrict__ enorm, float* __restrict__ out,
        float* __restrict__ partials) {
    __shared__ __align__(16) unsigned short b_s[2][BN * D];      // 128 KB, XOR-swizzled
    __shared__ unsigned long long cand[CAND_CAP];                // 24 KB
    __shared__ unsigned long long best[BM];                      // 512 B
    __shared__ unsigned int rmin[BM];                            // 256 B
    __shared__ float red[THREADS];                               // 2 KB
    __shared__ int candn;

    const int t = threadIdx.x;
    const int wid = t >> 6, l = t & 63;
    const int l31 = l & 31, lh = l >> 5;
    const int wm = wid >> 2, wn = wid & 3;
    const int rowbase = blockIdx.x * BM;

    float* qout = out;
    float* enc = out + (size_t)N * D;
    float* idxout = enc + (size_t)N * K;

    if (t < BM) { rmin[t] = RMIN_INIT; best[t] = ~0ull; }
    if (t == 0) candn = 0;

    // A fragments: wave's 32 rows = rowbase + wm*32 + l31
    short8 afr[8];
    {
        const int row = rowbase + wm * 32 + l31;
#pragma unroll
        for (int ks = 0; ks < 8; ++ks) {
            const float* xp = X + (size_t)row * D + ks * 16 + lh * 8;
            f32x4 v0 = *(const f32x4*)xp;
            f32x4 v1 = *(const f32x4*)(xp + 4);
            short8 a;
            a[0] = (short)f2bf(v0[0]); a[1] = (short)f2bf(v0[1]);
            a[2] = (short)f2bf(v0[2]); a[3] = (short)f2bf(v0[3]);
            a[4] = (short)f2bf(v1[0]); a[5] = (short)f2bf(v1[1]);
            a[6] = (short)f2bf(v1[2]); a[7] = (short)f2bf(v1[3]);
            afr[ks] = a;
        }
    }

    f32x4 sreg[8];
    {   // prologue: stage chunk 0 into buf 0
        const f32x4* gs = (const f32x4*)e1t;
#pragma unroll
        for (int i = 0; i < 8; ++i) sreg[i] = gs[t + THREADS * i];
#pragma unroll
        for (int i = 0; i < 8; ++i) {
            int unit = t + THREADS * i;
            int c = unit >> 4, slot = unit & 15;
            *(f32x4*)((char*)&b_s[0][0] + c * 256 + ((slot ^ (c & 15)) << 4)) = sreg[i];
        }
    }

    int cur = 0;
    for (int ch = 0; ch < NCH; ++ch) {
        if (ch + 1 < NCH) {
            const f32x4* gs = (const f32x4*)(e1t + (size_t)(ch + 1) * BN * D);
#pragma unroll
            for (int i = 0; i < 8; ++i) sreg[i] = gs[t + THREADS * i];
        }
        lds_barrier();   // buf[cur] + prev-chunk rmin visible; stores stay in flight

        const int chcol = ch * BN;

        // fused one-hot zero-fill issued FIRST: maximum in-flight window per chunk
        {
            const f32x4 z = {0.f, 0.f, 0.f, 0.f};
#pragma unroll
            for (int i = 0; i < 8; ++i) {
                int unit = t + THREADS * i;
                int row = unit >> 6, cu = unit & 63;
                __builtin_nontemporal_store(z,
                    (f32x4*)(enc + (size_t)(rowbase + row) * K + chcol + cu * 4));
            }
        }

        // per-row threshold cache (stale-safe: any observed value >= final)
        float thrv[16];
#pragma unroll
        for (int q = 0; q < 4; ++q) {
            const int base = wm * 32 + 4 * lh + 8 * q;
            uint4 rv = *(const uint4*)&rmin[base];
            thrv[4 * q + 0] = funsort(rv.x);
            thrv[4 * q + 1] = funsort(rv.y);
            thrv[4 * q + 2] = funsort(rv.z);
            thrv[4 * q + 3] = funsort(rv.w);
        }

        f32x16 acc[2];
#pragma unroll
        for (int nf = 0; nf < 2; ++nf)
#pragma unroll
            for (int r = 0; r < 16; ++r) acc[nf][r] = 0.f;

#pragma unroll
        for (int ks = 0; ks < 8; ++ks) {
            short8 bf[2];
#pragma unroll
            for (int nf = 0; nf < 2; ++nf) {
                int c = wn * 64 + nf * 32 + l31;
                int slot = ks * 2 + lh;
                bf[nf] = *(const short8*)((const char*)&b_s[cur][0] + c * 256 + ((slot ^ (c & 15)) << 4));
            }
#pragma unroll
            for (int nf = 0; nf < 2; ++nf)
                acc[nf] = __builtin_amdgcn_mfma_f32_32x32x16_bf16(afr[ks], bf[nf], acc[nf], 0, 0, 0);
        }

        float dts[2][16];
#pragma unroll
        for (int nf = 0; nf < 2; ++nf) {
            const int col = chcol + wn * 64 + nf * 32 + l31;
            const float en = enorm[col];
#pragma unroll
            for (int r = 0; r < 16; ++r) dts[nf][r] = en - 2.f * acc[nf][r];
        }

        // wave-level per-row-slot min over this chunk's 64 cols (tightens the
        // push gate BEFORE any push -> no candidate flooding in early chunks)
        float cmin[16];
#pragma unroll
        for (int r = 0; r < 16; ++r) cmin[r] = fminf(dts[0][r], dts[1][r]);
#pragma unroll
        for (int m = 1; m <= 16; m <<= 1)
#pragma unroll
            for (int r = 0; r < 16; ++r)
                cmin[r] = fminf(cmin[r], __shfl_xor(cmin[r], m, 64));

#pragma unroll
        for (int r = 0; r < 16; ++r) {
            const int ro = wm * 32 + 4 * lh + 8 * (r >> 2) + (r & 3);
            const float te = fminf(thrv[r], cmin[r]) + DELTA;
#pragma unroll
            for (int nf = 0; nf < 2; ++nf) {
                if (dts[nf][r] < te) {
                    const int col = chcol + wn * 64 + nf * 32 + l31;
                    int ci = atomicAdd(&candn, 1);
                    if (ci < CAND_CAP)
                        cand[ci] = ((unsigned long long)fsort(dts[nf][r]) << 32) |
                                   ((unsigned long long)ro << 13) | (unsigned)col;
                }
            }
            if (l31 == 0 && cmin[r] < thrv[r])
                atomicMin(&rmin[ro], fsort(cmin[r]));
        }

        if (ch + 1 < NCH) {
#pragma unroll
            for (int i = 0; i < 8; ++i) {
                int unit = t + THREADS * i;
                int c = unit >> 4, slot = unit & 15;
                *(f32x4*)((char*)&b_s[cur ^ 1][0] + c * 256 + ((slot ^ (c & 15)) << 4)) = sreg[i];
            }
        }
        cur ^= 1;
    }

    __syncthreads();   // FULL drain: zero-fill stores complete; rmin/cand final

    // ---- exact f32 verification of surviving candidates ----
    {
        int n = candn; if (n > CAND_CAP) n = CAND_CAP;
        for (int i = wid; i < n; i += 8) {     // one wave per candidate
            const unsigned long long e = cand[i];
            const float dta = funsort((unsigned int)(e >> 32));
            const int ro = (int)((e >> 13) & 63u);
            const int col = (int)(e & 8191u);
            if (dta < funsort(rmin[ro]) + DELTA) {
                const int row = rowbase + ro;
                float x0 = X[(size_t)row * D + l];
                float x1 = X[(size_t)row * D + 64 + l];
                float e0, e1;
                if (E2T) {
                    e0 = e2t[(size_t)col * D + l];
                    e1 = e2t[(size_t)col * D + 64 + l];
                } else {
                    e0 = E[(size_t)l * K + col];
                    e1 = E[(size_t)(l + 64) * K + col];
                }
                float s = x0 * e0 + x1 * e1;
#pragma unroll
                for (int m = 1; m <= 32; m <<= 1) s += __shfl_xor(s, m, 64);
                if (l == 0) {
                    float dtx = enorm[col] - 2.f * s;
                    atomicMin(&best[ro],
                        ((unsigned long long)fsort(dtx) << 32) | (unsigned)col);
                }
            }
        }
    }
    __syncthreads();

    // ---- outputs: indices, one-hot scatter, quantized, loss partial ----
    if (t < BM) {
        const int k = (int)(best[t] & 8191ull);
        idxout[rowbase + t] = (float)k;
        __builtin_nontemporal_store(1.0f, &enc[(size_t)(rowbase + t) * K + k]);
    }

    const int rr = t >> 3, sL = t & 7;
    const int row = rowbase + rr;
    const int kb = (int)(best[rr] & 8191ull);
    float part = 0.f;
#pragma unroll
    for (int j = 0; j < 4; ++j) {
        const int d0 = sL * 16 + 4 * j;
        f32x4 xv = *(const f32x4*)(X + (size_t)row * D + d0);
        f32x4 ev;
        if (E2T) {
            ev = *(const f32x4*)(e2t + (size_t)kb * D + d0);
        } else {
#pragma unroll
            for (int u = 0; u < 4; ++u) ev[u] = E[(size_t)(d0 + u) * K + kb];
        }
        f32x4 qv;
#pragma unroll
        for (int u = 0; u < 4; ++u) {
            float df = ev[u] - xv[u];
            qv[u] = xv[u] + df;
            part += df * df;
        }
        *(f32x4*)(qout + (size_t)row * D + d0) = qv;
    }
    red[t] = part;
    __syncthreads();
#pragma unroll
    for (int off = THREADS / 2; off > 0; off >>= 1) {
        if (t < off) red[t] += red[t + off];
        __syncthreads();
    }
    if (t == 0) partials[blockIdx.x] = red[0];
}

__global__ __launch_bounds__(256) void loss_kernel(const float* __restrict__ partials,
                                                   float* __restrict__ out) {
    __shared__ float red[256];
    const int t = threadIdx.x;
    red[t] = partials[t];
    __syncthreads();
    for (int off = 128; off > 0; off >>= 1) {
        if (t < off) red[t] += red[t + off];
        __syncthreads();
    }
    if (t == 0) {
        float mean = red[0] / (float)((size_t)N * D);
        out[(size_t)N * D + (size_t)N * K + N] = mean + 0.25f * mean;
    }
}

extern "C" void kernel_launch(void* const* d_in, const int* in_sizes, int n_in,
                              void* d_out, int out_size, void* d_ws, size_t ws_size,
                              hipStream_t stream) {
    const float* X = (const float*)d_in[0];
    const float* E = (const float*)d_in[1];
    float* out = (float*)d_out;
    char* ws = (char*)d_ws;

    const size_t E1T_B = (size_t)K * D * 2;          // 2 MB
    const size_t E2T_B = (size_t)K * D * 4;          // 4 MB
    const bool use_e2t = ws_size >= E1T_B + E2T_B + 64 * 1024;

    unsigned short* e1t = (unsigned short*)ws;
    float* e2t; float* enorm; float* partials;
    if (use_e2t) {
        e2t = (float*)(ws + E1T_B);
        enorm = (float*)(ws + E1T_B + E2T_B);
        partials = enorm + K;
    } else {
        e2t = nullptr;
        enorm = (float*)(ws + E1T_B);
        partials = enorm + K;
    }

    hipLaunchKernelGGL(prep_kernel, dim3(K / 32), dim3(256), 0, stream,
                       E, e1t, e2t, enorm);
    if (use_e2t)
        hipLaunchKernelGGL((main_kernel<1>), dim3(N / BM), dim3(THREADS), 0, stream,
                           X, E, e1t, e2t, enorm, out, partials);
    else
        hipLaunchKernelGGL((main_kernel<0>), dim3(N / BM), dim3(THREADS), 0, stream,
                           X, E, e1t, e2t, enorm, out, partials);
    hipLaunchKernelGGL(loss_kernel, dim3(1), dim3(256), 0, stream, partials, out);
}